// Round 9
// baseline (289.717 us; speedup 1.0000x reference)
//
#include <hip/hip_runtime.h>
#include <hip/hip_bf16.h>

typedef __attribute__((ext_vector_type(4))) float f32x4;
typedef __attribute__((ext_vector_type(8))) short s16x8;
typedef __attribute__((ext_vector_type(4))) short s16x4;

#define D_MODEL 1024
#define NH 16
#define HD 64
#define BB 4
#define TT 2048
#define MROWS (BB * TT) /* 8192 */
#define QSCALE 0.18033688011112042f /* 0.125 * log2(e): Q pre-scaled so softmax uses exp2 */

#define MFMA16(a, b, c) __builtin_amdgcn_mfma_f32_16x16x32_bf16(a, b, c, 0, 0, 0)

#if __has_builtin(__builtin_amdgcn_mfma_f32_16x16x16_bf16)
#define PVMFMA(a, b, c) __builtin_amdgcn_mfma_f32_16x16x16_bf16(a, b, c, 0, 0, 0)
#elif __has_builtin(__builtin_amdgcn_mfma_f32_16x16x16bf16_1k)
#define PVMFMA(a, b, c) __builtin_amdgcn_mfma_f32_16x16x16bf16_1k(a, b, c, 0, 0, 0)
#else
static __device__ __forceinline__ f32x4 pv_mfma_asm(s16x4 a, s16x4 b, f32x4 c) {
  asm volatile("v_mfma_f32_16x16x16_bf16 %0, %1, %2, %0\n\ts_nop 7\n\ts_nop 7"
               : "+v"(c)
               : "v"(a), "v"(b));
  return c;
}
#define PVMFMA(a, b, c) pv_mfma_asm(a, b, c)
#endif

#define GLL16(g, l)                                                                   \
  __builtin_amdgcn_global_load_lds((const __attribute__((address_space(1))) void*)(g), \
                                   (__attribute__((address_space(3))) void*)(l), 16, 0, 0)

static __device__ __forceinline__ unsigned short f2bf(float f) {
  unsigned int u = __float_as_uint(f);
  u += 0x7fff + ((u >> 16) & 1);  // round-to-nearest-even
  return (unsigned short)(u >> 16);
}

// ---------------- fp32 -> bf16 convert (x) ----------------
__global__ void k_convert(const float* __restrict__ src, short* __restrict__ dst, int n4) {
  int i = blockIdx.x * blockDim.x + threadIdx.x;
  if (i >= n4) return;
  f32x4 v = reinterpret_cast<const f32x4*>(src)[i];
  s16x4 o;
#pragma unroll
  for (int r = 0; r < 4; r++) o[r] = (short)f2bf(v[r]);
  reinterpret_cast<s16x4*>(dst)[i] = o;
}

// ---------------- transpose + convert: W [K][N] fp32 -> Wt [N][K] bf16 ----------------
__global__ void k_transpose(const float* __restrict__ src, short* __restrict__ dst, int K, int N) {
  __shared__ float tile[32][33];
  int n0 = blockIdx.x * 32, k0 = blockIdx.y * 32;
  int tx = threadIdx.x, ty = threadIdx.y;  // (32, 8)
#pragma unroll
  for (int i = 0; i < 4; i++) tile[ty + i * 8][tx] = src[(size_t)(k0 + ty + i * 8) * N + n0 + tx];
  __syncthreads();
#pragma unroll
  for (int i = 0; i < 4; i++)
    dst[(size_t)(n0 + ty + i * 8) * K + k0 + tx] = (short)f2bf(tile[tx][ty + i * 8]);
}

// ---------------- QKV GEMM: 256x128 tile, BK=64, 8 waves, 2-phase dbuf ----------------
// Parameter-scaled version of the verified 2-phase structure: STAGE(t+1) before
// compute(t), one __syncthreads per K-tile (vmcnt-drains the prefetch after the
// whole MFMA phase hid it). LDS rows are 128B => 16-way-conflict regime, so use
// the verified attn swizzle: pre-swizzled global source chunk + XOR'd reads.
// Grid 24x32 = 768 blocks = 3 exact block-waves at 1 block/CU (96KB LDS).
__global__ __launch_bounds__(512, 2) void k_gemm_qkv(
    const short* __restrict__ A, const short* __restrict__ Bt, const float* __restrict__ bias,
    short* __restrict__ outQ, short* __restrict__ outK, short* __restrict__ outV) {
  const int K = D_MODEL;
  __shared__ __align__(16) short lds_a[2][256 * 64];  // 64 KB
  __shared__ __align__(16) short lds_b[2][128 * 64];  // 32 KB
  const int tid = threadIdx.x;
  const int m0 = blockIdx.y * 256, n0 = blockIdx.x * 128;
  const int w = tid >> 6, lane = tid & 63;
  const int wm = (w >> 1) * 64, wn = (w & 1) * 64;  // 4M x 2N waves, 64x64 each
  const int lr = lane & 15, lg = lane >> 4;
  const int srow = lane >> 3;                // row within an 8-row gll
  const int scol = ((lane & 7) ^ srow) * 8;  // pre-swizzled source chunk (rule #21)
  const int r7 = lr & 7;                     // read-side swizzle key

  const short* aGb = A + (size_t)(m0 + w * 32 + srow) * K + scol;   // 4 gll: rows w*32+{0,8,16,24}
  const short* bGb = Bt + (size_t)(n0 + w * 16 + srow) * K + scol;  // 2 gll: rows w*16+{0,8}

#define QSTAGE(bi, kt)                                                \
  {                                                                   \
    GLL16(aGb + (kt), &lds_a[bi][(w * 32) * 64]);                     \
    GLL16(aGb + (size_t)8 * K + (kt), &lds_a[bi][(w * 32 + 8) * 64]); \
    GLL16(aGb + (size_t)16 * K + (kt), &lds_a[bi][(w * 32 + 16) * 64]); \
    GLL16(aGb + (size_t)24 * K + (kt), &lds_a[bi][(w * 32 + 24) * 64]); \
    GLL16(bGb + (kt), &lds_b[bi][(w * 16) * 64]);                     \
    GLL16(bGb + (size_t)8 * K + (kt), &lds_b[bi][(w * 16 + 8) * 64]); \
  }

  f32x4 acc[4][4] = {};
  const int NT = K / 64;  // 16 K-tiles
  QSTAGE(0, 0);
  __syncthreads();
  for (int t = 0; t < NT; ++t) {
    const int cur = t & 1;
    if (t + 1 < NT) QSTAGE(cur ^ 1, (t + 1) * 64);  // prefetch overlaps compute
#pragma unroll
    for (int ks = 0; ks < 2; ks++) {
      s16x8 af[4], bfg[4];
#pragma unroll
      for (int i = 0; i < 4; i++)
        af[i] = *(const s16x8*)&lds_a[cur][(wm + i * 16 + lr) * 64 + ((ks * 4 + lg) ^ r7) * 8];
#pragma unroll
      for (int j = 0; j < 4; j++)
        bfg[j] = *(const s16x8*)&lds_b[cur][(wn + j * 16 + lr) * 64 + ((ks * 4 + lg) ^ r7) * 8];
#pragma unroll
      for (int i = 0; i < 4; i++) {
#pragma unroll
        for (int j = 0; j < 4; j++) acc[i][j] = MFMA16(af[i], bfg[j], acc[i][j]);
      }
    }
    __syncthreads();  // drains prefetch vmcnt + protects buffer reuse
  }
#undef QSTAGE

  // epilogue: D layout col = lane&15 (N), row = 4*(lane>>4)+r (M) — HW-verified
#pragma unroll
  for (int j = 0; j < 4; j++) {
    const int ng = n0 + wn + j * 16 + lr;
    const float bv = bias[ng];
#pragma unroll
    for (int i = 0; i < 4; i++) {
      const int mg = m0 + wm + i * 16 + 4 * lg;
      const int sec = ng >> 10, c = ng & 1023, h = c >> 6, d = c & 63;
      const int b = mg >> 11, t = mg & 2047;
      const int bh = b * NH + h;
      if (sec == 2) {  // V: transposed layout, 4 consecutive t -> one 8B store
        s16x4 pk;
#pragma unroll
        for (int r = 0; r < 4; r++) pk[r] = (short)f2bf(acc[i][j][r] + bv);
        *(s16x4*)&outV[((size_t)bh * HD + d) * TT + t] = pk;
      } else {
        short* dst = (sec == 0) ? outQ : outK;
        const float sc = (sec == 0) ? QSCALE : 1.0f;
#pragma unroll
        for (int r = 0; r < 4; r++)
          dst[((size_t)bh * TT + t + r) * HD + d] = (short)f2bf((acc[i][j][r] + bv) * sc);
      }
    }
  }
}

// ---------------- proj GEMM (verified R8 kernel): 128x128, 3-buf counted vmcnt ----------------
__global__ __launch_bounds__(256, 3) void k_gemm_proj(
    const short* __restrict__ A, const short* __restrict__ Bt, const float* __restrict__ bias,
    float* __restrict__ outF) {
  const int K = D_MODEL, N = D_MODEL;
  __shared__ __align__(16) short lds_a[3][128 * 32];
  __shared__ __align__(16) short lds_b[3][128 * 32];
  const int tid = threadIdx.x;
  const int m0 = blockIdx.y * 128, n0 = blockIdx.x * 128;
  const int w = tid >> 6, lane = tid & 63;
  const int wm = (w >> 1) * 64, wn = (w & 1) * 64;
  const int lr = lane & 15, lg = lane >> 4;

  const short* aG = A + (size_t)(m0 + w * 32 + (lane >> 2)) * K + (lane & 3) * 8;
  const short* bG = Bt + (size_t)(n0 + w * 32 + (lane >> 2)) * K + (lane & 3) * 8;

#define GSTAGE(bi, kt)                                                 \
  {                                                                    \
    GLL16(aG + (kt), &lds_a[bi][(w * 32) * 32]);                       \
    GLL16(aG + (size_t)16 * K + (kt), &lds_a[bi][(w * 32 + 16) * 32]); \
    GLL16(bG + (kt), &lds_b[bi][(w * 32) * 32]);                       \
    GLL16(bG + (size_t)16 * K + (kt), &lds_b[bi][(w * 32 + 16) * 32]); \
  }

  f32x4 acc[4][4] = {};
  const int NT = K / 32;
  GSTAGE(0, 0);
  GSTAGE(1, 32);
  asm volatile("s_waitcnt vmcnt(4)" ::: "memory");
  __builtin_amdgcn_s_barrier();
  __builtin_amdgcn_sched_barrier(0);
  int cur = 0, nx2 = 2;
  for (int t = 0; t < NT; ++t) {
    if (t + 2 < NT) GSTAGE(nx2, (t + 2) * 32);
    s16x8 af[4], bfg[4];
#pragma unroll
    for (int i = 0; i < 4; i++)
      af[i] = *(const s16x8*)&lds_a[cur][(wm + i * 16 + lr) * 32 + lg * 8];
#pragma unroll
    for (int j = 0; j < 4; j++)
      bfg[j] = *(const s16x8*)&lds_b[cur][(wn + j * 16 + lr) * 32 + lg * 8];
#pragma unroll
    for (int i = 0; i < 4; i++) {
#pragma unroll
      for (int j = 0; j < 4; j++) acc[i][j] = MFMA16(af[i], bfg[j], acc[i][j]);
    }
    if (t + 2 < NT) {
      asm volatile("s_waitcnt vmcnt(4) lgkmcnt(0)" ::: "memory");
      __builtin_amdgcn_s_barrier();
      __builtin_amdgcn_sched_barrier(0);
    } else if (t + 1 < NT) {
      asm volatile("s_waitcnt vmcnt(0) lgkmcnt(0)" ::: "memory");
      __builtin_amdgcn_s_barrier();
      __builtin_amdgcn_sched_barrier(0);
    }
    cur = (cur == 2) ? 0 : cur + 1;
    nx2 = (nx2 == 2) ? 0 : nx2 + 1;
  }
#undef GSTAGE

#pragma unroll
  for (int j = 0; j < 4; j++) {
    const int ng = n0 + wn + j * 16 + lr;
    const float bv = bias[ng];
#pragma unroll
    for (int i = 0; i < 4; i++) {
      const int mg = m0 + wm + i * 16 + 4 * lg;
#pragma unroll
      for (int r = 0; r < 4; r++) outF[(size_t)(mg + r) * N + ng] = acc[i][j][r] + bv;
    }
  }
}

// ---------------- flash attention v7: v6 + XCD-affinity block remap ----------------
// Round-8 PMC: FETCH 255MB vs ~64MB ideal -> each bh's K/V re-fetched by its 16
// blocks spread over 8 non-coherent XCD L2s. Remap (bijective, 1024 = 8 x 128):
// all 16 q-blocks of one bh land on ONE XCD; 8 bh/XCD x 512KB K/V fits 4MB L2.
__global__ __launch_bounds__(256, 4) void k_attn(const short* __restrict__ Q,
                                                 const short* __restrict__ Kb,
                                                 const short* __restrict__ Vt,
                                                 short* __restrict__ Y) {
  __shared__ __align__(16) short kls[2][64 * 64];  // K tile [kv 64][d 64], swizzled
  __shared__ __align__(16) short vls[2][64 * 64];  // V^T tile [d 64][kv 64], swizzled
  const int tid = threadIdx.x, w = tid >> 6, lane = tid & 63;
  const int lr = lane & 15, lg = lane >> 4;
  // XCD-affinity remap: p = dispatch-linear id; xcd = p&7 (HW round-robin heuristic)
  const int p = blockIdx.x + 16 * blockIdx.y;
  const int xcd = p & 7, idx = p >> 3;
  const int bh = xcd * 8 + (idx >> 4);  // 8 bh per XCD
  const int xq = idx & 15;              // q-panel-pair index within bh
  const int b = bh >> 4, h = bh & 15;
  const short* Qh = Q + (size_t)bh * TT * HD;
  const short* Kh = Kb + (size_t)bh * TT * HD;
  const short* Vh = Vt + (size_t)bh * HD * TT;
  const int srow = lane >> 3;
  const int scol = ((lane & 7) ^ srow) * 8;  // pre-swizzled source col (rule #21)
  const int r7 = lr & 7;                     // read-side swizzle key
  const s16x4 vone = {(short)0x3F80, (short)0x3F80, (short)0x3F80, (short)0x3F80};

#define STAGE(bi, kv0)                                                   \
  {                                                                      \
    const short* ks_ = Kh + (size_t)((kv0) + w * 16 + srow) * HD + scol; \
    GLL16(ks_, &kls[bi][(w * 16) * 64]);                                 \
    GLL16(ks_ + 8 * HD, &kls[bi][(w * 16 + 8) * 64]);                    \
    const short* vs_ = Vh + (size_t)(w * 16 + srow) * TT + (kv0) + scol; \
    GLL16(vs_, &vls[bi][(w * 16) * 64]);                                 \
    GLL16(vs_ + 8 * TT, &vls[bi][(w * 16 + 8) * 64]);                    \
  }

#pragma unroll
  for (int ph = 0; ph < 2; ph++) {
    const int panel = ph ? (31 - xq) : xq;  // light first, heavy second
    const int q0w = panel * 64 + w * 16;
    s16x8 qf[2];
#pragma unroll
    for (int kc = 0; kc < 2; kc++)
      qf[kc] = *(const s16x8*)&Qh[(q0w + lr) * HD + kc * 32 + lg * 8];

    f32x4 sacc = {0.f, 0.f, 0.f, 0.f};  // denominator accumulator (ones-row MFMA)
    f32x4 oacc[4] = {};                 // y^T[d][q]: [jd], row d = 4lg+r, col q = lr

    const int nt = panel + 1;  // kv tiles 0..panel
    STAGE(0, 0);
    __syncthreads();
    for (int t = 0; t < nt; ++t) {
      const int cur = t & 1;
      if (t + 1 < nt) STAGE(cur ^ 1, (t + 1) * 64);  // prefetch overlaps compute
      const int kv0 = t * 64;
      // ---- QK^T: S^T = mfma(K, Q); kf from swizzled LDS ----
      s16x8 kf[4][2];
#pragma unroll
      for (int jk = 0; jk < 4; jk++)
#pragma unroll
        for (int kc = 0; kc < 2; kc++)
          kf[jk][kc] = *(const s16x8*)&kls[cur][(jk * 16 + lr) * 64 + ((kc * 4 + lg) ^ r7) * 8];
      f32x4 s[4] = {};
#pragma unroll
      for (int kc = 0; kc < 2; kc++)
#pragma unroll
        for (int jk = 0; jk < 4; jk++) s[jk] = MFMA16(kf[jk][kc], qf[kc], s[jk]);

      // ---- numerator, fixed max = 0; element: kv = kv0+16jk+4lg+r, q = lr ----
      const bool diag = (kv0 + 63 > q0w);  // wave-uniform
      const int qg = q0w + lr;
      s16x4 pf16[4];  // P in registers: B-frag of 16x16x16 (k = 4*lg + r)
#pragma unroll
      for (int jk = 0; jk < 4; jk++) {
#pragma unroll
        for (int r = 0; r < 4; r++) {
          float pp = exp2f(s[jk][r]);
          if (diag) {
            const int kvg = kv0 + jk * 16 + 4 * lg + r;
            pp = (kvg <= qg) ? pp : 0.f;
          }
          pf16[jk][r] = (short)((__float_as_uint(pp) + 0x8000) >> 16);
        }
      }
      // ---- PV + denominator: 4 K=16 slices, in-register P ----
#pragma unroll
      for (int jk = 0; jk < 4; jk++) {
        s16x4 vreg[4];
#pragma unroll
        for (int jd = 0; jd < 4; jd++)
          vreg[jd] = *(const s16x4*)&vls[cur][(jd * 16 + lr) * 64 +
                                              ((2 * jk + (lg >> 1)) ^ r7) * 8 + (lg & 1) * 4];
        sacc = PVMFMA(vone, pf16[jk], sacc);
#pragma unroll
        for (int jd = 0; jd < 4; jd++) oacc[jd] = PVMFMA(vreg[jd], pf16[jk], oacc[jd]);
      }
      __syncthreads();  // drains prefetch vmcnt + protects buffer reuse
    }
    // ---- epilogue: denom in sacc[0]; write Y [B][T][C] bf16 ----
    const float inv = 1.0f / sacc[0];
    const int trow = q0w + lr;
#pragma unroll
    for (int jd = 0; jd < 4; jd++) {
      s16x4 pk;
#pragma unroll
      for (int r = 0; r < 4; r++) pk[r] = (short)f2bf(oacc[jd][r] * inv);
      *(s16x4*)&Y[((size_t)(b * TT + trow)) * D_MODEL + h * HD + jd * 16 + 4 * lg] = pk;
    }
  }
#undef STAGE
}

extern "C" void kernel_launch(void* const* d_in, const int* in_sizes, int n_in,
                              void* d_out, int out_size, void* d_ws, size_t ws_size,
                              hipStream_t stream) {
  const float* x = (const float*)d_in[0];
  const float* Wqkv = (const float*)d_in[1];
  const float* bqkv = (const float*)d_in[2];
  const float* Wproj = (const float*)d_in[3];
  const float* bproj = (const float*)d_in[4];
  float* out = (float*)d_out;

  char* ws = (char*)d_ws;
  short* Xb = (short*)ws;                      // 16 MB  [8192][1024] bf16 (reused as Y)
  short* Wqkvt = (short*)(ws + (16u << 20));   // 6 MB   [3072][1024]
  short* Wprojt = (short*)(ws + (22u << 20));  // 2 MB   [1024][1024]
  short* Qb = (short*)(ws + (24u << 20));      // 16 MB  [64][2048][64] (pre-scaled)
  short* Kb = (short*)(ws + (40u << 20));      // 16 MB  [64][2048][64]
  short* Vtb = (short*)(ws + (56u << 20));     // 16 MB  [64][64][2048]  (V^T)
  short* Yb = Xb;                              // Xb dead after gemm_qkv

  k_convert<<<dim3(MROWS * D_MODEL / 4 / 256), 256, 0, stream>>>(x, Xb, MROWS * D_MODEL / 4);
  k_transpose<<<dim3(3 * D_MODEL / 32, D_MODEL / 32), dim3(32, 8), 0, stream>>>(
      Wqkv, Wqkvt, D_MODEL, 3 * D_MODEL);
  k_transpose<<<dim3(D_MODEL / 32, D_MODEL / 32), dim3(32, 8), 0, stream>>>(
      Wproj, Wprojt, D_MODEL, D_MODEL);
  k_gemm_qkv<<<dim3(3 * D_MODEL / 128, MROWS / 256), 512, 0, stream>>>(
      Xb, Wqkvt, bqkv, Qb, Kb, Vtb);
  k_attn<<<dim3(16, BB * NH), 256, 0, stream>>>(Qb, Kb, Vtb, Yb);
  k_gemm_proj<<<dim3(D_MODEL / 128, MROWS / 128), 256, 0, stream>>>(
      Yb, Wprojt, bproj, out);
}